// Round 3
// baseline (416.397 us; speedup 1.0000x reference)
//
#include <hip/hip_runtime.h>
#include <cstdint>
#include <cstddef>

// DigitCapsules routing: B=256, R=1152, C=10, IC=8, OC=16, 3 iters.
// R20: R18's recompute-u pass (lane-local softmax, c in regs) was
// L2-LATENCY-bound ONLY because grid=512 blocks (2/CU, 8 waves/CU,
// Occ 19%). W logical traffic is independent of the r-split, so
// NSPLIT 2->6 gives 1536 blocks = 24 waves/CU for free. R19's
// cross-thread softmax (LDS-pipe saturated, 91 us) is abandoned.
//   L1 s1cvt (R18 verbatim): x.W f32 -> part1 bf16; emits xf16+wf16.
//   L2 s1_reduce (R15 verbatim): vsum1 = squash(0.1*sum part1).
//   L3 pass(xf16,wf16,v1 -> pA [6][256][160] f32)   NSPLIT=6, NSWEEP=3
//   L4 red6(pA, v1 -> v2): v1 + squash(sum_sp pA)
//   L5 pass(xf16,wf16,v2 -> pB)
//   L6 red6(pB, null -> out): squash(sum_sp pB)
// Logits linear in v: b_t = u.(v1+..+v_{t-1}) -> running vsum (proven).
// Pass inner loop byte-identical to R18 (passed, absmax 0.0039);
// __launch_bounds__(256,6) pins VGPR<=85 (R18 measured 84).
#define NB 256
#define NR 1152
#define NC 10
#define NI 8
#define NO 16
#define NSPLIT 6
#define NSWEEP 3     // r-sweeps per pass thread: 3*64 = 192 = NR/NSPLIT
#define NRC 144      // r-chunks in s1cvt (8 r each)

typedef _Float16 h2 __attribute__((ext_vector_type(2)));

#if defined(__has_builtin)
#if __has_builtin(__builtin_amdgcn_fdot2)
#define HAS_FDOT2 1
#endif
#if __has_builtin(__builtin_amdgcn_cvt_pkrtz)
#define HAS_PKRTZ 1
#endif
#endif

static __device__ __forceinline__ float fdot2(uint32_t a, uint32_t b, float c) {
#ifdef HAS_FDOT2
    return __builtin_amdgcn_fdot2(__builtin_bit_cast(h2, a),
                                  __builtin_bit_cast(h2, b), c, false);
#else
    const h2 av = __builtin_bit_cast(h2, a);
    const h2 bv = __builtin_bit_cast(h2, b);
    c = fmaf((float)av.x, (float)bv.x, c);
    return fmaf((float)av.y, (float)bv.y, c);
#endif
}

static __device__ __forceinline__ uint32_t pk_f16(float a, float b) {
#ifdef HAS_PKRTZ
    return __builtin_bit_cast(uint32_t, __builtin_amdgcn_cvt_pkrtz(a, b));
#else
    h2 v; v.x = (_Float16)a; v.y = (_Float16)b;
    return __builtin_bit_cast(uint32_t, v);
#endif
}

static __device__ __forceinline__ uint32_t bf16_pack2(float lo, float hi) {
    uint32_t vl = __float_as_uint(lo);
    vl = vl + 0x7FFFu + ((vl >> 16) & 1u);
    uint32_t vh = __float_as_uint(hi);
    vh = vh + 0x7FFFu + ((vh >> 16) & 1u);
    return (vl >> 16) | (vh & 0xFFFF0000u);
}

// -------------------------------------------------------------------------
// caps_s1cvt: 2304 blocks = 144 rc x 16 bg; 320 thr = c*32 + rl*4 + oq.
// W[r][c][i][oq*4..+3] = 8 float4 in regs; 16-deep b-loop; fused s1 partial
// via rl-shuffle-reduce -> packed bf16 part1 (uint2). No u store.
// Side outputs: xf16 [b][r][8] f16; wf16 [r][c][oq][16 u32] (bg==0 only).
__global__ __launch_bounds__(320) void caps_s1cvt_kernel(
    const float* __restrict__ x, const float* __restrict__ W,
    uint32_t* __restrict__ part1, uint32_t* __restrict__ xf16,
    uint32_t* __restrict__ wf16)
{
    const int t  = threadIdx.x;
    const int c  = t >> 5;             // 0..9
    const int rl = (t & 31) >> 2;      // 0..7
    const int oq = t & 3;              // 0..3
    const int rc = blockIdx.x >> 4;    // 0..143
    const int bg = blockIdx.x & 15;    // 0..15
    const int b0 = bg * 16;
    const int r  = rc * 8 + rl;

    __shared__ float xs[16][8][8];     // 4 KB

    if (t < 256) {                     // 256 float4 = x[b0..+16)[rc*8..+8)[8]
        const int bi = t >> 4, rem = t & 15;
        const int rr = rem >> 1, hf = rem & 1;
        const float4 xv =
            *(const float4*)(x + ((size_t)(b0 + bi) * NR + rc * 8 + rr) * 8 + hf * 4);
        *(float4*)&xs[bi][rr][hf * 4] = xv;
        uint2 xp;                      // f16 conversion (unique per block)
        xp.x = pk_f16(xv.x, xv.y);
        xp.y = pk_f16(xv.z, xv.w);
        *(uint2*)(xf16 + ((size_t)(b0 + bi) * NR + rc * 8 + rr) * 4 + hf * 2) = xp;
    }

    const float* wb = W + ((size_t)r * NC + c) * (NI * NO) + oq * 4;
    float4 wf[8];
#pragma unroll
    for (int i = 0; i < 8; ++i) wf[i] = *(const float4*)(wb + i * NO);

    if (bg == 0) {                     // W f16 conversion, once per element
        const float* wfl = (const float*)wf;   // wfl[i*4+od]
        uint32_t* dst = wf16 + (((size_t)r * NC + c) * 4 + oq) * 16;
#pragma unroll
        for (int od = 0; od < 4; ++od) {
            uint4 wq;
            wq.x = pk_f16(wfl[0 * 4 + od], wfl[1 * 4 + od]);
            wq.y = pk_f16(wfl[2 * 4 + od], wfl[3 * 4 + od]);
            wq.z = pk_f16(wfl[4 * 4 + od], wfl[5 * 4 + od]);
            wq.w = pk_f16(wfl[6 * 4 + od], wfl[7 * 4 + od]);
            *(uint4*)(dst + od * 4) = wq;
        }
    }

    __syncthreads();

#pragma unroll 2
    for (int bi = 0; bi < 16; ++bi) {
        const float4 xv4a = *(const float4*)&xs[bi][rl][0];
        const float4 xv4b = *(const float4*)&xs[bi][rl][4];
        const float xr[8] = {xv4a.x, xv4a.y, xv4a.z, xv4a.w,
                             xv4b.x, xv4b.y, xv4b.z, xv4b.w};
        float ax = 0.f, ay = 0.f, az = 0.f, aw = 0.f;
#pragma unroll
        for (int i = 0; i < 8; ++i) {
            const float xv = xr[i];
            ax = fmaf(xv, wf[i].x, ax); ay = fmaf(xv, wf[i].y, ay);
            az = fmaf(xv, wf[i].z, az); aw = fmaf(xv, wf[i].w, aw);
        }
        // fused s1 partial: reduce fp32 quad over rl (lane bits 2..4)
        float sx = ax, sy = ay, sz = az, sw = aw;
#pragma unroll
        for (int off = 4; off <= 16; off <<= 1) {
            sx += __shfl_xor(sx, off); sy += __shfl_xor(sy, off);
            sz += __shfl_xor(sz, off); sw += __shfl_xor(sw, off);
        }
        if ((t & 28) == 0) {   // rl == 0 lanes: one uint2 per (bi,c,oq)
            uint2 p;
            p.x = bf16_pack2(sx, sy);
            p.y = bf16_pack2(sz, sw);
            *(uint2*)(part1 + ((size_t)(b0 + bi) * NRC + rc) * 80
                      + c * 8 + oq * 2) = p;
        }
    }
}

// -------------------------------------------------------------------------
// s1_reduce: vsum = squash(0.1 * sum over 144 rc of bf16 part1).
// grid 256 (b), 192 thr (160 active; t = c*16 + o).   (R15 verbatim)
__global__ __launch_bounds__(192) void caps_s1_reduce_kernel(
    const uint32_t* __restrict__ part1, float* __restrict__ vsum)
{
    const int b = blockIdx.x;
    const int t = threadIdx.x;
    if (t >= 160) return;
    const uint32_t* p = part1 + (size_t)b * NRC * 80 + (t >> 1);
    const bool hi = t & 1;
    float s0 = 0.f, s1 = 0.f, s2 = 0.f, s3 = 0.f;
#pragma unroll 4
    for (int g = 0; g < NRC; g += 4) {
        const uint32_t w0 = p[(g + 0) * 80];
        const uint32_t w1 = p[(g + 1) * 80];
        const uint32_t w2 = p[(g + 2) * 80];
        const uint32_t w3 = p[(g + 3) * 80];
        s0 += hi ? __uint_as_float(w0 & 0xFFFF0000u) : __uint_as_float(w0 << 16);
        s1 += hi ? __uint_as_float(w1 & 0xFFFF0000u) : __uint_as_float(w1 << 16);
        s2 += hi ? __uint_as_float(w2 & 0xFFFF0000u) : __uint_as_float(w2 << 16);
        s3 += hi ? __uint_as_float(w3 & 0xFFFF0000u) : __uint_as_float(w3 << 16);
    }
    const float s = 0.1f * ((s0 + s1) + (s2 + s3));
    float n2 = s * s;
    n2 += __shfl_xor(n2, 1);
    n2 += __shfl_xor(n2, 2);
    n2 += __shfl_xor(n2, 4);
    n2 += __shfl_xor(n2, 8);
    const float nrm = sqrtf(n2);
    vsum[(size_t)b * 160 + t] = s * (n2 / (1.f + n2) / (nrm + 1e-8f));
}

// -------------------------------------------------------------------------
// Routing pass (R20): block = (b, sp 0..5), 256 thr = 64 rl x 4 oq,
// NSWEEP=3 sweeps of 64 r. Per (r,c): 4x dwordx4 of wf16 (L2-hot) + 16
// fdot2 -> u[4]; lane-local softmax over c; weighted acc; one rl-reduce
// at end -> fp32 partial [sp][b][160]. Inner body identical to R18.
__global__ __launch_bounds__(256, 6) void caps_pass_f16_kernel(
    const uint32_t* __restrict__ xf16, const uint32_t* __restrict__ wf16,
    const float* __restrict__ vsum, float* __restrict__ partout)
{
    const int b  = blockIdx.x % NB;
    const int sp = blockIdx.x / NB;
    const int t  = threadIdx.x;
    const int oq = t & 3;
    const int rl = t >> 2;    // 0..63

    __shared__ float vss[160];
    __shared__ float sred[4][160];

    if (t < 160) vss[t] = vsum[(size_t)b * 160 + t];
    __syncthreads();

    float acc[10][4];
#pragma unroll
    for (int c = 0; c < 10; ++c)
#pragma unroll
        for (int j = 0; j < 4; ++j) acc[c][j] = 0.f;

#pragma unroll 1
    for (int k = 0; k < NSWEEP; ++k) {
        const int r = sp * (NSWEEP * 64) + k * 64 + rl;
        const uint4 xv = *(const uint4*)(xf16 + ((size_t)b * NR + r) * 4);

        float us[10][4];
        float lg[10];
#pragma unroll
        for (int c = 0; c < 10; ++c) {
            const uint4* wp =
                (const uint4*)(wf16 + (((size_t)r * NC + c) * 4 + oq) * 16);
            const uint4 w0 = wp[0], w1 = wp[1], w2 = wp[2], w3 = wp[3];
            float u0 = fdot2(xv.x, w0.x, 0.f);
            u0 = fdot2(xv.y, w0.y, u0);
            u0 = fdot2(xv.z, w0.z, u0);
            u0 = fdot2(xv.w, w0.w, u0);
            float u1 = fdot2(xv.x, w1.x, 0.f);
            u1 = fdot2(xv.y, w1.y, u1);
            u1 = fdot2(xv.z, w1.z, u1);
            u1 = fdot2(xv.w, w1.w, u1);
            float u2 = fdot2(xv.x, w2.x, 0.f);
            u2 = fdot2(xv.y, w2.y, u2);
            u2 = fdot2(xv.z, w2.z, u2);
            u2 = fdot2(xv.w, w2.w, u2);
            float u3 = fdot2(xv.x, w3.x, 0.f);
            u3 = fdot2(xv.y, w3.y, u3);
            u3 = fdot2(xv.z, w3.z, u3);
            u3 = fdot2(xv.w, w3.w, u3);
            us[c][0] = u0; us[c][1] = u1; us[c][2] = u2; us[c][3] = u3;
            const float4 vq = *(const float4*)&vss[c * 16 + oq * 4];
            float d = u0 * vq.x;
            d = fmaf(u1, vq.y, d);
            d = fmaf(u2, vq.z, d);
            d = fmaf(u3, vq.w, d);
            lg[c] = d;
        }
#pragma unroll
        for (int c = 0; c < 10; ++c) {    // finish o-dot over 4 oq lanes
            lg[c] += __shfl_xor(lg[c], 1);
            lg[c] += __shfl_xor(lg[c], 2);
        }
        float m = lg[0];
#pragma unroll
        for (int c = 1; c < 10; ++c) m = fmaxf(m, lg[c]);
        float wgt[10], ssum = 0.f;
#pragma unroll
        for (int c = 0; c < 10; ++c) { wgt[c] = __expf(lg[c] - m); ssum += wgt[c]; }
        const float inv = 1.f / ssum;
#pragma unroll
        for (int c = 0; c < 10; ++c) {
            const float wv = wgt[c] * inv;
            acc[c][0] = fmaf(wv, us[c][0], acc[c][0]);
            acc[c][1] = fmaf(wv, us[c][1], acc[c][1]);
            acc[c][2] = fmaf(wv, us[c][2], acc[c][2]);
            acc[c][3] = fmaf(wv, us[c][3], acc[c][3]);
        }
    }

    // in-wave reduce over 16 rl-lanes (lane bits 2..5) — once per kernel
#pragma unroll
    for (int off = 4; off <= 32; off <<= 1)
#pragma unroll
        for (int c = 0; c < 10; ++c)
#pragma unroll
            for (int j = 0; j < 4; ++j) acc[c][j] += __shfl_xor(acc[c][j], off);

    const int wv = t >> 6;
    if ((t & 63) < 4) {
#pragma unroll
        for (int c = 0; c < 10; ++c)
#pragma unroll
            for (int j = 0; j < 4; ++j)
                sred[wv][c * 16 + oq * 4 + j] = acc[c][j];
    }
    __syncthreads();

    if (t < 160) {
        partout[((size_t)sp * NB + b) * 160 + t]
            = sred[0][t] + sred[1][t] + sred[2][t] + sred[3][t];
    }
}

// -------------------------------------------------------------------------
// red6: outv = (vprev? vprev : 0) + squash(sum over 6 sp of part).
// grid 256 (b), 192 thr (160 active). Coalesced 640-B rows.
__global__ __launch_bounds__(192) void caps_red6_kernel(
    const float* __restrict__ part, const float* __restrict__ vprev,
    float* __restrict__ outv)
{
    const int b = blockIdx.x;
    const int t = threadIdx.x;
    if (t >= 160) return;
    float s = 0.f;
#pragma unroll
    for (int sp = 0; sp < NSPLIT; ++sp)
        s += part[((size_t)sp * NB + b) * 160 + t];
    float n2 = s * s;
    n2 += __shfl_xor(n2, 1);
    n2 += __shfl_xor(n2, 2);
    n2 += __shfl_xor(n2, 4);
    n2 += __shfl_xor(n2, 8);
    const float nrm = sqrtf(n2);
    float v = s * (n2 / (1.f + n2) / (nrm + 1e-8f));
    if (vprev != nullptr) v += vprev[(size_t)b * 160 + t];
    outv[(size_t)b * 160 + t] = v;
}

// -------------------------------------------------------------------------
extern "C" void kernel_launch(void* const* d_in, const int* in_sizes, int n_in,
                              void* d_out, int out_size, void* d_ws, size_t ws_size,
                              hipStream_t stream) {
    const float* x = (const float*)d_in[0];   // [256,1152,8]
    const float* W = (const float*)d_in[1];   // [1,1152,10,8,16]
    float* out = (float*)d_out;               // [256,10,16] = [256][160]

    // ws: part1 [256][144][80]u32 = 11,796,480
    //     xf16  [256][1152][8]f16 =  4,718,592
    //     wf16  [1152][10][4][16] =  2,949,120
    //     pA [6][256][160]f = 983,040 | pB 983,040
    //     v1 163,840 | v2 163,840           (total 21,757,952 B)
    uint8_t*  ws   = (uint8_t*)d_ws;
    uint32_t* prt1 = (uint32_t*)ws;
    uint32_t* xf16 = (uint32_t*)(ws + 11796480u);
    uint32_t* wf16 = (uint32_t*)(ws + 16515072u);
    float*    pA   = (float*)(ws + 19464192u);
    float*    pB   = (float*)(ws + 20447232u);
    float*    v1   = (float*)(ws + 21430272u);
    float*    v2   = (float*)(ws + 21594112u);

    caps_s1cvt_kernel    <<<2304, 320, 0, stream>>>(x, W, prt1, xf16, wf16);
    caps_s1_reduce_kernel<<<NB, 192, 0, stream>>>(prt1, v1);
    caps_pass_f16_kernel <<<NB * NSPLIT, 256, 0, stream>>>(xf16, wf16, v1, pA);
    caps_red6_kernel     <<<NB, 192, 0, stream>>>(pA, v1, v2);
    caps_pass_f16_kernel <<<NB * NSPLIT, 256, 0, stream>>>(xf16, wf16, v2, pB);
    caps_red6_kernel     <<<NB, 192, 0, stream>>>(pB, nullptr, out);
}

// Round 4
// 332.341 us; speedup vs baseline: 1.2529x; 1.2529x over previous
//
#include <hip/hip_runtime.h>
#include <cstdint>
#include <cstddef>

// DigitCapsules routing: B=256, R=1152, C=10, IC=8, OC=16, 3 iters.
// R21 = R20 with the spill bug fixed. R20's __launch_bounds__(256,6)
// capped VGPR at 40 (needed 84) -> us[10][4]/acc spilled to scratch:
// pass FETCH 166 MB + WRITE 184 MB of scratch traffic, VALU 7.6%,
// 163 us. Revert to R18's proven (256,2) [VGPR=84, no spill]: at 84
// VGPRs the HW naturally residents floor(512/84)=6 waves/SIMD; the
// NSPLIT=6 grid (1536 blocks = 6/CU) fills it. Everything else is
// R20/R18 verbatim.
//   L1 s1cvt (R18 verbatim): x.W f32 -> part1 bf16; emits xf16+wf16.
//   L2 s1_reduce (R15 verbatim): vsum1 = squash(0.1*sum part1).
//   L3 pass(xf16,wf16,v1 -> pA [6][256][160] f32)   NSPLIT=6, NSWEEP=3
//   L4 red6(pA, v1 -> v2): v1 + squash(sum_sp pA)
//   L5 pass(xf16,wf16,v2 -> pB)
//   L6 red6(pB, null -> out): squash(sum_sp pB)
// Logits linear in v: b_t = u.(v1+..+v_{t-1}) -> running vsum (proven).
#define NB 256
#define NR 1152
#define NC 10
#define NI 8
#define NO 16
#define NSPLIT 6
#define NSWEEP 3     // r-sweeps per pass thread: 3*64 = 192 = NR/NSPLIT
#define NRC 144      // r-chunks in s1cvt (8 r each)

typedef _Float16 h2 __attribute__((ext_vector_type(2)));

#if defined(__has_builtin)
#if __has_builtin(__builtin_amdgcn_fdot2)
#define HAS_FDOT2 1
#endif
#if __has_builtin(__builtin_amdgcn_cvt_pkrtz)
#define HAS_PKRTZ 1
#endif
#endif

static __device__ __forceinline__ float fdot2(uint32_t a, uint32_t b, float c) {
#ifdef HAS_FDOT2
    return __builtin_amdgcn_fdot2(__builtin_bit_cast(h2, a),
                                  __builtin_bit_cast(h2, b), c, false);
#else
    const h2 av = __builtin_bit_cast(h2, a);
    const h2 bv = __builtin_bit_cast(h2, b);
    c = fmaf((float)av.x, (float)bv.x, c);
    return fmaf((float)av.y, (float)bv.y, c);
#endif
}

static __device__ __forceinline__ uint32_t pk_f16(float a, float b) {
#ifdef HAS_PKRTZ
    return __builtin_bit_cast(uint32_t, __builtin_amdgcn_cvt_pkrtz(a, b));
#else
    h2 v; v.x = (_Float16)a; v.y = (_Float16)b;
    return __builtin_bit_cast(uint32_t, v);
#endif
}

static __device__ __forceinline__ uint32_t bf16_pack2(float lo, float hi) {
    uint32_t vl = __float_as_uint(lo);
    vl = vl + 0x7FFFu + ((vl >> 16) & 1u);
    uint32_t vh = __float_as_uint(hi);
    vh = vh + 0x7FFFu + ((vh >> 16) & 1u);
    return (vl >> 16) | (vh & 0xFFFF0000u);
}

// -------------------------------------------------------------------------
// caps_s1cvt: 2304 blocks = 144 rc x 16 bg; 320 thr = c*32 + rl*4 + oq.
// W[r][c][i][oq*4..+3] = 8 float4 in regs; 16-deep b-loop; fused s1 partial
// via rl-shuffle-reduce -> packed bf16 part1 (uint2). No u store.
// Side outputs: xf16 [b][r][8] f16; wf16 [r][c][oq][16 u32] (bg==0 only).
__global__ __launch_bounds__(320) void caps_s1cvt_kernel(
    const float* __restrict__ x, const float* __restrict__ W,
    uint32_t* __restrict__ part1, uint32_t* __restrict__ xf16,
    uint32_t* __restrict__ wf16)
{
    const int t  = threadIdx.x;
    const int c  = t >> 5;             // 0..9
    const int rl = (t & 31) >> 2;      // 0..7
    const int oq = t & 3;              // 0..3
    const int rc = blockIdx.x >> 4;    // 0..143
    const int bg = blockIdx.x & 15;    // 0..15
    const int b0 = bg * 16;
    const int r  = rc * 8 + rl;

    __shared__ float xs[16][8][8];     // 4 KB

    if (t < 256) {                     // 256 float4 = x[b0..+16)[rc*8..+8)[8]
        const int bi = t >> 4, rem = t & 15;
        const int rr = rem >> 1, hf = rem & 1;
        const float4 xv =
            *(const float4*)(x + ((size_t)(b0 + bi) * NR + rc * 8 + rr) * 8 + hf * 4);
        *(float4*)&xs[bi][rr][hf * 4] = xv;
        uint2 xp;                      // f16 conversion (unique per block)
        xp.x = pk_f16(xv.x, xv.y);
        xp.y = pk_f16(xv.z, xv.w);
        *(uint2*)(xf16 + ((size_t)(b0 + bi) * NR + rc * 8 + rr) * 4 + hf * 2) = xp;
    }

    const float* wb = W + ((size_t)r * NC + c) * (NI * NO) + oq * 4;
    float4 wf[8];
#pragma unroll
    for (int i = 0; i < 8; ++i) wf[i] = *(const float4*)(wb + i * NO);

    if (bg == 0) {                     // W f16 conversion, once per element
        const float* wfl = (const float*)wf;   // wfl[i*4+od]
        uint32_t* dst = wf16 + (((size_t)r * NC + c) * 4 + oq) * 16;
#pragma unroll
        for (int od = 0; od < 4; ++od) {
            uint4 wq;
            wq.x = pk_f16(wfl[0 * 4 + od], wfl[1 * 4 + od]);
            wq.y = pk_f16(wfl[2 * 4 + od], wfl[3 * 4 + od]);
            wq.z = pk_f16(wfl[4 * 4 + od], wfl[5 * 4 + od]);
            wq.w = pk_f16(wfl[6 * 4 + od], wfl[7 * 4 + od]);
            *(uint4*)(dst + od * 4) = wq;
        }
    }

    __syncthreads();

#pragma unroll 2
    for (int bi = 0; bi < 16; ++bi) {
        const float4 xv4a = *(const float4*)&xs[bi][rl][0];
        const float4 xv4b = *(const float4*)&xs[bi][rl][4];
        const float xr[8] = {xv4a.x, xv4a.y, xv4a.z, xv4a.w,
                             xv4b.x, xv4b.y, xv4b.z, xv4b.w};
        float ax = 0.f, ay = 0.f, az = 0.f, aw = 0.f;
#pragma unroll
        for (int i = 0; i < 8; ++i) {
            const float xv = xr[i];
            ax = fmaf(xv, wf[i].x, ax); ay = fmaf(xv, wf[i].y, ay);
            az = fmaf(xv, wf[i].z, az); aw = fmaf(xv, wf[i].w, aw);
        }
        // fused s1 partial: reduce fp32 quad over rl (lane bits 2..4)
        float sx = ax, sy = ay, sz = az, sw = aw;
#pragma unroll
        for (int off = 4; off <= 16; off <<= 1) {
            sx += __shfl_xor(sx, off); sy += __shfl_xor(sy, off);
            sz += __shfl_xor(sz, off); sw += __shfl_xor(sw, off);
        }
        if ((t & 28) == 0) {   // rl == 0 lanes: one uint2 per (bi,c,oq)
            uint2 p;
            p.x = bf16_pack2(sx, sy);
            p.y = bf16_pack2(sz, sw);
            *(uint2*)(part1 + ((size_t)(b0 + bi) * NRC + rc) * 80
                      + c * 8 + oq * 2) = p;
        }
    }
}

// -------------------------------------------------------------------------
// s1_reduce: vsum = squash(0.1 * sum over 144 rc of bf16 part1).
// grid 256 (b), 192 thr (160 active; t = c*16 + o).   (R15 verbatim)
__global__ __launch_bounds__(192) void caps_s1_reduce_kernel(
    const uint32_t* __restrict__ part1, float* __restrict__ vsum)
{
    const int b = blockIdx.x;
    const int t = threadIdx.x;
    if (t >= 160) return;
    const uint32_t* p = part1 + (size_t)b * NRC * 80 + (t >> 1);
    const bool hi = t & 1;
    float s0 = 0.f, s1 = 0.f, s2 = 0.f, s3 = 0.f;
#pragma unroll 4
    for (int g = 0; g < NRC; g += 4) {
        const uint32_t w0 = p[(g + 0) * 80];
        const uint32_t w1 = p[(g + 1) * 80];
        const uint32_t w2 = p[(g + 2) * 80];
        const uint32_t w3 = p[(g + 3) * 80];
        s0 += hi ? __uint_as_float(w0 & 0xFFFF0000u) : __uint_as_float(w0 << 16);
        s1 += hi ? __uint_as_float(w1 & 0xFFFF0000u) : __uint_as_float(w1 << 16);
        s2 += hi ? __uint_as_float(w2 & 0xFFFF0000u) : __uint_as_float(w2 << 16);
        s3 += hi ? __uint_as_float(w3 & 0xFFFF0000u) : __uint_as_float(w3 << 16);
    }
    const float s = 0.1f * ((s0 + s1) + (s2 + s3));
    float n2 = s * s;
    n2 += __shfl_xor(n2, 1);
    n2 += __shfl_xor(n2, 2);
    n2 += __shfl_xor(n2, 4);
    n2 += __shfl_xor(n2, 8);
    const float nrm = sqrtf(n2);
    vsum[(size_t)b * 160 + t] = s * (n2 / (1.f + n2) / (nrm + 1e-8f));
}

// -------------------------------------------------------------------------
// Routing pass (R21): block = (b, sp 0..5), 256 thr = 64 rl x 4 oq,
// NSWEEP=3 sweeps of 64 r. Per (r,c): 4x dwordx4 of wf16 (L2-hot) + 16
// fdot2 -> u[4]; lane-local softmax over c; weighted acc; one rl-reduce
// at end -> fp32 partial [sp][b][160]. Inner body identical to R18;
// launch_bounds (256,2) = R18's proven VGPR=84, no spill.
__global__ __launch_bounds__(256, 2) void caps_pass_f16_kernel(
    const uint32_t* __restrict__ xf16, const uint32_t* __restrict__ wf16,
    const float* __restrict__ vsum, float* __restrict__ partout)
{
    const int b  = blockIdx.x % NB;
    const int sp = blockIdx.x / NB;
    const int t  = threadIdx.x;
    const int oq = t & 3;
    const int rl = t >> 2;    // 0..63

    __shared__ float vss[160];
    __shared__ float sred[4][160];

    if (t < 160) vss[t] = vsum[(size_t)b * 160 + t];
    __syncthreads();

    float acc[10][4];
#pragma unroll
    for (int c = 0; c < 10; ++c)
#pragma unroll
        for (int j = 0; j < 4; ++j) acc[c][j] = 0.f;

#pragma unroll 1
    for (int k = 0; k < NSWEEP; ++k) {
        const int r = sp * (NSWEEP * 64) + k * 64 + rl;
        const uint4 xv = *(const uint4*)(xf16 + ((size_t)b * NR + r) * 4);

        float us[10][4];
        float lg[10];
#pragma unroll
        for (int c = 0; c < 10; ++c) {
            const uint4* wp =
                (const uint4*)(wf16 + (((size_t)r * NC + c) * 4 + oq) * 16);
            const uint4 w0 = wp[0], w1 = wp[1], w2 = wp[2], w3 = wp[3];
            float u0 = fdot2(xv.x, w0.x, 0.f);
            u0 = fdot2(xv.y, w0.y, u0);
            u0 = fdot2(xv.z, w0.z, u0);
            u0 = fdot2(xv.w, w0.w, u0);
            float u1 = fdot2(xv.x, w1.x, 0.f);
            u1 = fdot2(xv.y, w1.y, u1);
            u1 = fdot2(xv.z, w1.z, u1);
            u1 = fdot2(xv.w, w1.w, u1);
            float u2 = fdot2(xv.x, w2.x, 0.f);
            u2 = fdot2(xv.y, w2.y, u2);
            u2 = fdot2(xv.z, w2.z, u2);
            u2 = fdot2(xv.w, w2.w, u2);
            float u3 = fdot2(xv.x, w3.x, 0.f);
            u3 = fdot2(xv.y, w3.y, u3);
            u3 = fdot2(xv.z, w3.z, u3);
            u3 = fdot2(xv.w, w3.w, u3);
            us[c][0] = u0; us[c][1] = u1; us[c][2] = u2; us[c][3] = u3;
            const float4 vq = *(const float4*)&vss[c * 16 + oq * 4];
            float d = u0 * vq.x;
            d = fmaf(u1, vq.y, d);
            d = fmaf(u2, vq.z, d);
            d = fmaf(u3, vq.w, d);
            lg[c] = d;
        }
#pragma unroll
        for (int c = 0; c < 10; ++c) {    // finish o-dot over 4 oq lanes
            lg[c] += __shfl_xor(lg[c], 1);
            lg[c] += __shfl_xor(lg[c], 2);
        }
        float m = lg[0];
#pragma unroll
        for (int c = 1; c < 10; ++c) m = fmaxf(m, lg[c]);
        float wgt[10], ssum = 0.f;
#pragma unroll
        for (int c = 0; c < 10; ++c) { wgt[c] = __expf(lg[c] - m); ssum += wgt[c]; }
        const float inv = 1.f / ssum;
#pragma unroll
        for (int c = 0; c < 10; ++c) {
            const float wv = wgt[c] * inv;
            acc[c][0] = fmaf(wv, us[c][0], acc[c][0]);
            acc[c][1] = fmaf(wv, us[c][1], acc[c][1]);
            acc[c][2] = fmaf(wv, us[c][2], acc[c][2]);
            acc[c][3] = fmaf(wv, us[c][3], acc[c][3]);
        }
    }

    // in-wave reduce over 16 rl-lanes (lane bits 2..5) — once per kernel
#pragma unroll
    for (int off = 4; off <= 32; off <<= 1)
#pragma unroll
        for (int c = 0; c < 10; ++c)
#pragma unroll
            for (int j = 0; j < 4; ++j) acc[c][j] += __shfl_xor(acc[c][j], off);

    const int wv = t >> 6;
    if ((t & 63) < 4) {
#pragma unroll
        for (int c = 0; c < 10; ++c)
#pragma unroll
            for (int j = 0; j < 4; ++j)
                sred[wv][c * 16 + oq * 4 + j] = acc[c][j];
    }
    __syncthreads();

    if (t < 160) {
        partout[((size_t)sp * NB + b) * 160 + t]
            = sred[0][t] + sred[1][t] + sred[2][t] + sred[3][t];
    }
}

// -------------------------------------------------------------------------
// red6: outv = (vprev? vprev : 0) + squash(sum over 6 sp of part).
// grid 256 (b), 192 thr (160 active). Coalesced 640-B rows.
__global__ __launch_bounds__(192) void caps_red6_kernel(
    const float* __restrict__ part, const float* __restrict__ vprev,
    float* __restrict__ outv)
{
    const int b = blockIdx.x;
    const int t = threadIdx.x;
    if (t >= 160) return;
    float s = 0.f;
#pragma unroll
    for (int sp = 0; sp < NSPLIT; ++sp)
        s += part[((size_t)sp * NB + b) * 160 + t];
    float n2 = s * s;
    n2 += __shfl_xor(n2, 1);
    n2 += __shfl_xor(n2, 2);
    n2 += __shfl_xor(n2, 4);
    n2 += __shfl_xor(n2, 8);
    const float nrm = sqrtf(n2);
    float v = s * (n2 / (1.f + n2) / (nrm + 1e-8f));
    if (vprev != nullptr) v += vprev[(size_t)b * 160 + t];
    outv[(size_t)b * 160 + t] = v;
}

// -------------------------------------------------------------------------
extern "C" void kernel_launch(void* const* d_in, const int* in_sizes, int n_in,
                              void* d_out, int out_size, void* d_ws, size_t ws_size,
                              hipStream_t stream) {
    const float* x = (const float*)d_in[0];   // [256,1152,8]
    const float* W = (const float*)d_in[1];   // [1,1152,10,8,16]
    float* out = (float*)d_out;               // [256,10,16] = [256][160]

    // ws: part1 [256][144][80]u32 = 11,796,480
    //     xf16  [256][1152][8]f16 =  4,718,592
    //     wf16  [1152][10][4][16] =  2,949,120
    //     pA [6][256][160]f = 983,040 | pB 983,040
    //     v1 163,840 | v2 163,840           (total 21,757,952 B)
    uint8_t*  ws   = (uint8_t*)d_ws;
    uint32_t* prt1 = (uint32_t*)ws;
    uint32_t* xf16 = (uint32_t*)(ws + 11796480u);
    uint32_t* wf16 = (uint32_t*)(ws + 16515072u);
    float*    pA   = (float*)(ws + 19464192u);
    float*    pB   = (float*)(ws + 20447232u);
    float*    v1   = (float*)(ws + 21430272u);
    float*    v2   = (float*)(ws + 21594112u);

    caps_s1cvt_kernel    <<<2304, 320, 0, stream>>>(x, W, prt1, xf16, wf16);
    caps_s1_reduce_kernel<<<NB, 192, 0, stream>>>(prt1, v1);
    caps_pass_f16_kernel <<<NB * NSPLIT, 256, 0, stream>>>(xf16, wf16, v1, pA);
    caps_red6_kernel     <<<NB, 192, 0, stream>>>(pA, v1, v2);
    caps_pass_f16_kernel <<<NB * NSPLIT, 256, 0, stream>>>(xf16, wf16, v2, pB);
    caps_red6_kernel     <<<NB, 192, 0, stream>>>(pB, nullptr, out);
}

// Round 5
// 138.239 us; speedup vs baseline: 3.0121x; 2.4041x over previous
//
#include <hip/hip_runtime.h>
#include <cstdint>
#include <cstddef>

// DigitCapsules routing: B=256, R=1152, C=10, IC=8, OC=16, 3 iters.
// R22: revert to the PROVEN 139-us u-materialized baseline (R15/R17);
// recompute-u direction abandoned after R18-R21 (best 195; the scattered
// W-gather pass is latency-bound and does not scale with occupancy:
// R18 51us @ Occ 19% -> R21 127us @ Occ 32%, L2 rate 14.5 -> 5.8 TB/s).
// Single change vs R17: FOLD s1_reduce INTO pass1's prologue (the pass
// kernel already has a proven prologue fold slot — pass2's part_prev
// path). pass1's 160 active threads run the verbatim s1_reduce loop over
// part1 (144 bf16 chunks, scale 0.1, squash), write vsum (both sp-blocks
// write identical bits — benign), then sweep. Deletes 1 kernel + 1 gap
// (~7.5us) for ~3-4us of duplicated L2/L3-warm prologue reads.
//   L1 caps_u_s1: u bf16 (94 MB) + fused pass-0 partial -> part1 bf16.
//   L2 caps_pass (pass1): prologue vsum=squash(0.1*sum part1); 9 uint2
//      sweeps; partials -> p2a.  (s1_reduce folded here)
//   L3 caps_pass (pass2): prologue folds vsum += squash(sum p2a); -> p2b.
//   L4 caps_final: out = squash(sum p2b).
// Measured structural walls (prior session): pass u-read 2.6 TB/s logical
// ~83% of ~3.15 TB/s read ceiling (6 variants >= 36 us); caps_u_s1
// pipe-sum ~44 us; cooperative fusion rejected by harness (R16).
// Logits linear in v: b_t = u.(v1+..+v_{t-1}) -> running vsum, 1 pass/iter.
#define NB 256
#define NR 1152
#define NC 10
#define NI 8
#define NO 16
#define NSPLIT 2
#define NSWEEP 9     // r-sweeps per pass thread: 9*64 = 576 = NR/NSPLIT
#define NRC 144      // r-chunks in caps_u_s1 (8 r each)

static __device__ __forceinline__ uint32_t bf16_pack2(float lo, float hi) {
    uint32_t vl = __float_as_uint(lo);
    vl = vl + 0x7FFFu + ((vl >> 16) & 1u);
    uint32_t vh = __float_as_uint(hi);
    vh = vh + 0x7FFFu + ((vh >> 16) & 1u);
    return (vl >> 16) | (vh & 0xFFFF0000u);
}

// -------------------------------------------------------------------------
// caps_u_s1: 2304 blocks = 144 rc x 16 bg; 320 thr = c*32 + rl*4 + oq.
// W[r][c][i][oq*4..+3] = 8 float4 in regs; 16-deep b-loop; u-store uint2;
// fused s1 partial via rl-shuffle-reduce -> packed bf16 part1 (uint2).
__global__ __launch_bounds__(320) void caps_u_s1_kernel(
    const float* __restrict__ x, const float* __restrict__ W,
    uint32_t* __restrict__ u, uint32_t* __restrict__ part1)
{
    const int t  = threadIdx.x;
    const int c  = t >> 5;             // 0..9
    const int rl = (t & 31) >> 2;      // 0..7
    const int oq = t & 3;              // 0..3
    const int rc = blockIdx.x >> 4;    // 0..143
    const int bg = blockIdx.x & 15;    // 0..15
    const int b0 = bg * 16;
    const int r  = rc * 8 + rl;

    __shared__ float xs[16][8][8];     // 4 KB

    if (t < 256) {                     // 256 float4 = x[b0..+16)[rc*8..+8)[8]
        const int bi = t >> 4, rem = t & 15;
        const int rr = rem >> 1, hf = rem & 1;
        *(float4*)&xs[bi][rr][hf * 4] =
            *(const float4*)(x + ((size_t)(b0 + bi) * NR + rc * 8 + rr) * 8 + hf * 4);
    }

    const float* wb = W + ((size_t)r * NC + c) * (NI * NO) + oq * 4;
    float4 wf[8];
#pragma unroll
    for (int i = 0; i < 8; ++i) wf[i] = *(const float4*)(wb + i * NO);

    __syncthreads();

#pragma unroll 2
    for (int bi = 0; bi < 16; ++bi) {
        const float4 xv4a = *(const float4*)&xs[bi][rl][0];
        const float4 xv4b = *(const float4*)&xs[bi][rl][4];
        const float xr[8] = {xv4a.x, xv4a.y, xv4a.z, xv4a.w,
                             xv4b.x, xv4b.y, xv4b.z, xv4b.w};
        float ax = 0.f, ay = 0.f, az = 0.f, aw = 0.f;
#pragma unroll
        for (int i = 0; i < 8; ++i) {
            const float xv = xr[i];
            ax = fmaf(xv, wf[i].x, ax); ay = fmaf(xv, wf[i].y, ay);
            az = fmaf(xv, wf[i].z, az); aw = fmaf(xv, wf[i].w, aw);
        }
        uint2 s;
        s.x = bf16_pack2(ax, ay);
        s.y = bf16_pack2(az, aw);
        *(uint2*)(u + (((size_t)(b0 + bi) * NC + c) * NR + r) * 8 + oq * 2) = s;

        // fused s1 partial: reduce fp32 quad over rl (lane bits 2..4)
        float sx = ax, sy = ay, sz = az, sw = aw;
#pragma unroll
        for (int off = 4; off <= 16; off <<= 1) {
            sx += __shfl_xor(sx, off); sy += __shfl_xor(sy, off);
            sz += __shfl_xor(sz, off); sw += __shfl_xor(sw, off);
        }
        if ((t & 28) == 0) {   // rl == 0 lanes: one uint2 per (bi,c,oq)
            uint2 p;
            p.x = bf16_pack2(sx, sy);
            p.y = bf16_pack2(sz, sw);
            *(uint2*)(part1 + ((size_t)(b0 + bi) * NRC + rc) * 80
                      + c * 8 + oq * 2) = p;
        }
    }
}

// -------------------------------------------------------------------------
// Routing pass (R8/R12 proven main loop): block = (b, sp), 256 thr =
// 64 rl x 4 oq, NSWEEP=9 sweeps of uint2.
// Prologue (pass1, part_prev==nullptr): vss = squash(0.1*sum of 144 bf16
//   part1 chunks) [s1_reduce folded, verbatim loop]; also writes vsum.
// Prologue (pass2): vss = vsum + squash(sum of 2 fp32 part_prev).
// Main sweep -> partout [sp][b][160] fp32.
__global__ __launch_bounds__(256, 2) void caps_pass_kernel(
    const uint32_t* __restrict__ u, const uint32_t* __restrict__ part1,
    float* __restrict__ vsum, const float* __restrict__ part_prev,
    float* __restrict__ partout)
{
    const int b  = blockIdx.x >> 1;
    const int sp = blockIdx.x & 1;
    const int t  = threadIdx.x;
    const int oq = t & 3;
    const int rl = t >> 2;    // 0..63

    __shared__ float vss[160];
    __shared__ float sred[4][160];

    if (t < 160) {
        float v;
        if (part_prev != nullptr) {       // pass2: vsum + squash(s2)
            const float s = part_prev[(size_t)b * 160 + t]
                          + part_prev[((size_t)NB + b) * 160 + t];
            float n2 = s * s;
            n2 += __shfl_xor(n2, 1);
            n2 += __shfl_xor(n2, 2);
            n2 += __shfl_xor(n2, 4);
            n2 += __shfl_xor(n2, 8);
            const float nrm = sqrtf(n2);
            v = vsum[(size_t)b * 160 + t]
              + s * (n2 / (1.f + n2) / (nrm + 1e-8f));
        } else {                          // pass1: s1_reduce folded
            const uint32_t* p = part1 + (size_t)b * NRC * 80 + (t >> 1);
            const bool hi = t & 1;
            float s0 = 0.f, s1 = 0.f, s2 = 0.f, s3 = 0.f;
#pragma unroll 4
            for (int g = 0; g < NRC; g += 4) {
                const uint32_t w0 = p[(g + 0) * 80];
                const uint32_t w1 = p[(g + 1) * 80];
                const uint32_t w2 = p[(g + 2) * 80];
                const uint32_t w3 = p[(g + 3) * 80];
                s0 += hi ? __uint_as_float(w0 & 0xFFFF0000u) : __uint_as_float(w0 << 16);
                s1 += hi ? __uint_as_float(w1 & 0xFFFF0000u) : __uint_as_float(w1 << 16);
                s2 += hi ? __uint_as_float(w2 & 0xFFFF0000u) : __uint_as_float(w2 << 16);
                s3 += hi ? __uint_as_float(w3 & 0xFFFF0000u) : __uint_as_float(w3 << 16);
            }
            const float s = 0.1f * ((s0 + s1) + (s2 + s3));
            float n2 = s * s;
            n2 += __shfl_xor(n2, 1);
            n2 += __shfl_xor(n2, 2);
            n2 += __shfl_xor(n2, 4);
            n2 += __shfl_xor(n2, 8);
            const float nrm = sqrtf(n2);
            v = s * (n2 / (1.f + n2) / (nrm + 1e-8f));
            // both sp-blocks write identical bits (same inputs/code) —
            // benign duplicate store; pass2 reads it next launch.
            vsum[(size_t)b * 160 + t] = v;
        }
        vss[t] = v;
    }
    __syncthreads();

    float acc[10][4];
#pragma unroll
    for (int c = 0; c < 10; ++c)
#pragma unroll
        for (int j = 0; j < 4; ++j) acc[c][j] = 0.f;

    const uint2* ub = (const uint2*)u + (size_t)b * NC * NR * 4 + oq;

    for (int k = 0; k < NSWEEP; ++k) {
        const int r = sp * (NSWEEP * 64) + k * 64 + rl;
        uint2 q[10];
#pragma unroll
        for (int c = 0; c < 10; ++c) q[c] = ub[((size_t)c * NR + r) * 4];

        float lg[10];
#pragma unroll
        for (int c = 0; c < 10; ++c) {
            const float4 vq = *(const float4*)&vss[c * 16 + oq * 4];
            float d = __uint_as_float(q[c].x << 16) * vq.x;
            d = fmaf(__uint_as_float(q[c].x & 0xFFFF0000u), vq.y, d);
            d = fmaf(__uint_as_float(q[c].y << 16),         vq.z, d);
            d = fmaf(__uint_as_float(q[c].y & 0xFFFF0000u), vq.w, d);
            lg[c] = d;
        }
#pragma unroll
        for (int c = 0; c < 10; ++c) {    // finish o-dot over 4 oq lanes
            lg[c] += __shfl_xor(lg[c], 1);
            lg[c] += __shfl_xor(lg[c], 2);
        }
        float m = lg[0];
#pragma unroll
        for (int c = 1; c < 10; ++c) m = fmaxf(m, lg[c]);
        float wgt[10], ssum = 0.f;
#pragma unroll
        for (int c = 0; c < 10; ++c) { wgt[c] = __expf(lg[c] - m); ssum += wgt[c]; }
        const float inv = 1.f / ssum;
#pragma unroll
        for (int c = 0; c < 10; ++c) {
            const float wv = wgt[c] * inv;
            acc[c][0] = fmaf(wv, __uint_as_float(q[c].x << 16),         acc[c][0]);
            acc[c][1] = fmaf(wv, __uint_as_float(q[c].x & 0xFFFF0000u), acc[c][1]);
            acc[c][2] = fmaf(wv, __uint_as_float(q[c].y << 16),         acc[c][2]);
            acc[c][3] = fmaf(wv, __uint_as_float(q[c].y & 0xFFFF0000u), acc[c][3]);
        }
    }

    // in-wave reduce over 16 rl-lanes (tid bits 2..5) — once per 9 r
#pragma unroll
    for (int off = 4; off <= 32; off <<= 1)
#pragma unroll
        for (int c = 0; c < 10; ++c)
#pragma unroll
            for (int j = 0; j < 4; ++j) acc[c][j] += __shfl_xor(acc[c][j], off);

    const int wv = t >> 6;
    if ((t & 63) < 4) {
#pragma unroll
        for (int c = 0; c < 10; ++c)
#pragma unroll
            for (int j = 0; j < 4; ++j)
                sred[wv][c * 16 + oq * 4 + j] = acc[c][j];
    }
    __syncthreads();

    if (t < 160) {
        partout[((size_t)sp * NB + b) * 160 + t]
            = sred[0][t] + sred[1][t] + sred[2][t] + sred[3][t];
    }
}

// -------------------------------------------------------------------------
// final: out = squash(sum of 2 partials). grid=256 (b), 192 thr.
__global__ __launch_bounds__(192) void caps_final_kernel(
    const float* __restrict__ p2b, float* __restrict__ out)
{
    const int b = blockIdx.x;
    const int t = threadIdx.x;
    if (t >= 160) return;
    const float s = p2b[(size_t)b * 160 + t]
                  + p2b[((size_t)NB + b) * 160 + t];
    float n2 = s * s;
    n2 += __shfl_xor(n2, 1);
    n2 += __shfl_xor(n2, 2);
    n2 += __shfl_xor(n2, 4);
    n2 += __shfl_xor(n2, 8);
    const float nrm   = sqrtf(n2);
    const float scale = n2 / (1.f + n2) / (nrm + 1e-8f);
    out[(size_t)b * 160 + t] = scale * s;
}

// -------------------------------------------------------------------------
extern "C" void kernel_launch(void* const* d_in, const int* in_sizes, int n_in,
                              void* d_out, int out_size, void* d_ws, size_t ws_size,
                              hipStream_t stream) {
    const float* x = (const float*)d_in[0];   // [256,1152,8]
    const float* W = (const float*)d_in[1];   // [1,1152,10,8,16]
    float* out = (float*)d_out;               // [256,10,16]

    // ws: u 94,371,840 | part1 bf16 [256][144][80 u32] = 11,796,480
    //     p2a [2][256][160]f = 327,680 | p2b 327,680 | vsum 163,840
    uint8_t*  ws   = (uint8_t*)d_ws;
    uint32_t* u    = (uint32_t*)ws;
    uint32_t* prt1 = (uint32_t*)(ws + 94371840u);
    float*    p2a  = (float*)(ws + 94371840u + 11796480u);
    float*    p2b  = (float*)(ws + 94371840u + 11796480u + 327680u);
    float*    vsm  = (float*)(ws + 94371840u + 11796480u + 655360u);

    caps_u_s1_kernel<<<2304, 320, 0, stream>>>(x, W, u, prt1);
    caps_pass_kernel<<<NB * NSPLIT, 256, 0, stream>>>(u, prt1, vsm, nullptr, p2a);
    caps_pass_kernel<<<NB * NSPLIT, 256, 0, stream>>>(u, nullptr, vsm, p2a, p2b);
    caps_final_kernel<<<NB, 192, 0, stream>>>(p2b, out);
}